// Round 7
// baseline (87.007 us; speedup 1.0000x reference)
//
#include <hip/hip_runtime.h>
#include <hip/hip_bf16.h>
#include <float.h>

// RigidityLoss: M=16384 gathered points, brute-force KNN (K=8) + loss.
// R6: distance matrix on the MFMA pipe. t[r][c] = -2*dot(q_r,p_c) + sq_c via
// mfma_f32_16x16x32_f16 (A rows = (-2x,-2y,-2z) f16, B cols = (x,y,z) f16,
// C=0; sq_c added in f32 during packing). Selection = 17 VALU / 256 evals
// (4 add + 4 pack + 1 idx + 4 med3 + 4 min). No LDS/barriers in k_knn:
// B-blobs read straight from L2 (256B replicated-coalesced per tile).
// 8 candidate splits x 16-row tiles -> 8192 waves (32/CU). Keys (dist-high
// bits | idx) -> ws; merge kernel extracts global top-8 from 8 sorted lists
// (8 lanes/row) and computes the loss with exact f32 d2 recompute.

#define MPTS 16384
#define KNN  8
#define CDIM 16
#define LAMW 0.1f
#define EPSV 1e-6f

#define NSPLIT 8
#define CSPL  (MPTS/NSPLIT)    // 2048 candidates per split
#define TILES (CSPL/16)        // 128 cand-tiles per wave

#define MED3 __builtin_amdgcn_fmed3f
typedef __attribute__((ext_vector_type(8))) _Float16 f16x8;
typedef __attribute__((ext_vector_type(4))) float    f32x4;

__global__ __launch_bounds__(256) void k_gather(
    const float* __restrict__ canon, const float* __restrict__ trans,
    const int* __restrict__ indice, float4* __restrict__ c4,
    _Float16* __restrict__ bf16b, _Float16* __restrict__ af16b,
    float* __restrict__ sqf, float* __restrict__ acc)
{
    int t = blockIdx.x * 256 + threadIdx.x;
    if (t == 0) { acc[0] = 0.f; acc[1] = 0.f; }
    if (t < MPTS) {
        int j = indice[t];
        float x = canon[3*j+0] + trans[3*j+0];
        float y = canon[3*j+1] + trans[3*j+1];
        float z = canon[3*j+2] + trans[3*j+2];
        float sq = fmaf(x, x, fmaf(y, y, z*z));
        c4[t] = make_float4(-2.f*x, -2.f*y, -2.f*z, sq);   // exact recompute blob
        f16x8 bb = {};
        bb[0] = (_Float16)x; bb[1] = (_Float16)y; bb[2] = (_Float16)z;
        *(f16x8*)(bf16b + (size_t)t*8) = bb;
        f16x8 aa = {};
        aa[0] = (_Float16)(-2.f*x); aa[1] = (_Float16)(-2.f*y); aa[2] = (_Float16)(-2.f*z);
        *(f16x8*)(af16b + (size_t)t*8) = aa;
        sqf[t] = sq;
    }
}

__global__ __launch_bounds__(256, 8) void k_knn(
    const _Float16* __restrict__ bf16b, const _Float16* __restrict__ af16b,
    const float* __restrict__ sqf, float* __restrict__ keys)
{
    const int tid  = threadIdx.x;
    const int lane = tid & 63;
    const int wid  = (blockIdx.x << 2) | (tid >> 6);    // 0..8191
    const int rowtile = wid >> 3;                        // 0..1023
    const int split   = wid & (NSPLIT-1);
    const int rowbase = rowtile * 16;
    const int cbeg    = split * CSPL;
    const int lc      = lane & 15;                       // col / frag slot

    // A fragment: lane l<16 holds row (rowbase+l), k=0..7; lanes>=16 zero.
    f16x8 afrag = *(const f16x8*)(af16b + (size_t)(rowbase + lc) * 8);
    if (lane >= 16) { f16x8 zz = {}; afrag = zz; }
    f32x4 zero4 = {0.f, 0.f, 0.f, 0.f};

    const _Float16* bptr  = bf16b + (size_t)(cbeg + lc) * 8;
    const float*    sqptr = sqf + cbeg + lc;
    const unsigned  HMASK = 0xFFFFC000u;
    const unsigned  ivb   = (unsigned)(cbeg + lc);

    // 4 row-states (acc reg g -> row = (lane>>4)*4 + g), top-2 each
    float e00=FLT_MAX,e01=FLT_MAX, e10=FLT_MAX,e11=FLT_MAX;
    float e20=FLT_MAX,e21=FLT_MAX, e30=FLT_MAX,e31=FLT_MAX;

    #pragma unroll 4
    for (int tile = 0; tile < TILES; ++tile) {
        f16x8 b  = *(const f16x8*)(bptr + (size_t)tile * 128);  // garbage on k>=8 lanes: killed by A zeros
        float sq = sqptr[(size_t)tile * 16];
        f32x4 dv = __builtin_amdgcn_mfma_f32_16x16x32_f16(afrag, b, zero4, 0, 0, 0);
        unsigned iv = ivb + (unsigned)(tile * 16);
        float k0 = __uint_as_float((__float_as_uint(dv[0] + sq) & HMASK) | iv);
        float k1 = __uint_as_float((__float_as_uint(dv[1] + sq) & HMASK) | iv);
        float k2 = __uint_as_float((__float_as_uint(dv[2] + sq) & HMASK) | iv);
        float k3 = __uint_as_float((__float_as_uint(dv[3] + sq) & HMASK) | iv);
        e01=MED3(e00,e01,k0); e00=fminf(e00,k0);
        e11=MED3(e10,e11,k1); e10=fminf(e10,k1);
        e21=MED3(e20,e21,k2); e20=fminf(e20,k2);
        e31=MED3(e30,e31,k3); e30=fminf(e30,k3);
    }

    // Per row-state g: extract top-8 from 16 lanes x top-2 (within 16-groups),
    // write sorted 8-list for (split, row).
#define EXTRACT(EA, EB, G)                                                  \
    {                                                                       \
        float kres = FLT_MAX;                                               \
        _Pragma("unroll")                                                   \
        for (int s = 0; s < KNN; ++s) {                                     \
            float m = EA;                                                   \
            m = fminf(m, __shfl_xor(m, 1));                                 \
            m = fminf(m, __shfl_xor(m, 2));                                 \
            m = fminf(m, __shfl_xor(m, 4));                                 \
            m = fminf(m, __shfl_xor(m, 8));                                 \
            bool mine = (EA == m);      /* keys unique (idx in low bits) */ \
            kres = (lc == s) ? m : kres;                                    \
            EA = mine ? EB : EA;                                            \
            EB = mine ? FLT_MAX : EB;                                       \
        }                                                                   \
        if (lc < KNN)                                                       \
            keys[((size_t)split * MPTS + rowbase + (lane >> 4) * 4 + (G)) * KNN + lc] = kres; \
    }
    EXTRACT(e00, e01, 0)
    EXTRACT(e10, e11, 1)
    EXTRACT(e20, e21, 2)
    EXTRACT(e30, e31, 3)
#undef EXTRACT
}

__global__ __launch_bounds__(256) void k_merge_loss(
    const float4* __restrict__ c4, const float* __restrict__ keys,
    const int* __restrict__ indice, const float* __restrict__ motion,
    const float* __restrict__ fdc, float* __restrict__ acc)
{
    __shared__ float rS[4], rM[4];
    const int tid  = threadIdx.x;
    const int lane = tid & 63;
    const int wv   = tid >> 6;
    const int wid  = blockIdx.x * 4 + wv;
    const int r    = lane >> 3;          // row within wave: 0..7
    const int sp   = lane & 7;           // split (then neighbor slot k)
    const int row  = wid * 8 + r;

    // load this (row, split)'s sorted 8-list into named regs
    const float4* kp = (const float4*)(keys + ((size_t)sp * MPTS + row) * KNN);
    float4 K0 = kp[0], K1 = kp[1];
    float a0=K0.x,a1=K0.y,a2=K0.z,a3=K0.w,a4=K1.x,a5=K1.y,a6=K1.z,a7=K1.w;

    // 8-round extraction among the 8 lanes of this row: after round s,
    // lane s holds the s-th smallest key of the row's 64 candidates.
    float kres = FLT_MAX;
    #pragma unroll
    for (int s = 0; s < KNN; ++s) {
        float m = a0;
        m = fminf(m, __shfl_xor(m, 1));
        m = fminf(m, __shfl_xor(m, 2));
        m = fminf(m, __shfl_xor(m, 4));
        bool mine = (a0 == m);           // keys unique
        kres = (sp == s) ? m : kres;
        float n0=mine?a1:a0, n1=mine?a2:a1, n2=mine?a3:a2, n3=mine?a4:a3;
        float n4=mine?a5:a4, n5=mine?a6:a5, n6=mine?a7:a6, n7=mine?FLT_MAX:a7;
        a0=n0;a1=n1;a2=n2;a3=n3;a4=n4;a5=n5;a6=n6;a7=n7;
    }

    // ---- loss: lane (r, k=sp) handles neighbor k of its row ----
    float4 rc = c4[row];
    const float qx=-0.5f*rc.x, qy=-0.5f*rc.y, qz=-0.5f*rc.z, qq=rc.w;

    int jk = (int)(__float_as_uint(kres) & 0x3FFFu);
    float4 nc = c4[jk];
    // exact squared distance (same expanded form as reference)
    float te  = fmaf(qx, nc.x, fmaf(qy, nc.y, fmaf(qz, nc.z, nc.w)));
    float d2k = qq + te;

    float xn = -0.5f*nc.x, yn = -0.5f*nc.y, zn = -0.5f*nc.z;
    float sx = xn, sy = yn, sz = zn;
    sx += __shfl_xor(sx, 1); sx += __shfl_xor(sx, 2); sx += __shfl_xor(sx, 4);
    sy += __shfl_xor(sy, 1); sy += __shfl_xor(sy, 2); sy += __shfl_xor(sy, 4);
    sz += __shfl_xor(sz, 1); sz += __shfl_xor(sz, 2); sz += __shfl_xor(sz, 4);

    float surf = 0.f;
    if (sp == 0) {
        float dx = qx - sx * 0.125f + EPSV;
        float dy = qy - sy * 0.125f + EPSV;
        float dz = qz - sz * 0.125f + EPSV;
        surf = sqrtf(fmaf(dx, dx, fmaf(dy, dy, dz * dz)));
    }

    int irow = indice[row];
    int inb  = indice[jk];
    float c0v = fdc[3*irow+0] - fdc[3*inb+0] + EPSV;
    float c1v = fdc[3*irow+1] - fdc[3*inb+1] + EPSV;
    float c2v = fdc[3*irow+2] - fdc[3*inb+2] + EPSV;
    float cd2 = fmaf(c0v, c0v, fmaf(c1v, c1v, c2v * c2v));
    float w = __expf(-LAMW * fmaf(d2k, d2k, cd2));      // dist_w * color_w fused

    const float4* mr4 = (const float4*)(motion + CDIM * irow);
    const float4* mn4 = (const float4*)(motion + CDIM * inb);
    float s = 0.f;
    #pragma unroll
    for (int c = 0; c < CDIM/4; ++c) {
        float4 A = mr4[c], B = mn4[c];
        float g0 = A.x-B.x+EPSV, g1 = A.y-B.y+EPSV;
        float g2 = A.z-B.z+EPSV, g3 = A.w-B.w+EPSV;
        s = fmaf(g0,g0, fmaf(g1,g1, fmaf(g2,g2, fmaf(g3,g3, s))));
    }
    float simv = w * sqrtf(s);

    // ---- block reduction ----
    float aS = surf, aM = simv;
    #pragma unroll
    for (int m = 1; m <= 32; m <<= 1) {
        aS += __shfl_xor(aS, m);
        aM += __shfl_xor(aM, m);
    }
    if (lane == 0) { rS[wv] = aS; rM[wv] = aM; }
    __syncthreads();
    if (tid == 0) {
        float tS = 0.f, tM = 0.f;
        #pragma unroll
        for (int w2 = 0; w2 < 4; ++w2) { tS += rS[w2]; tM += rM[w2]; }
        atomicAdd(&acc[0], tS);
        atomicAdd(&acc[1], tM);
    }
}

__global__ void k_final(const float* __restrict__ acc, float* __restrict__ out)
{
    out[0] = acc[0] * (1.0f / MPTS) + acc[1] * (1.0f / (MPTS * KNN));
}

extern "C" void kernel_launch(void* const* d_in, const int* in_sizes, int n_in,
                              void* d_out, int out_size, void* d_ws, size_t ws_size,
                              hipStream_t stream)
{
    const float* canon  = (const float*)d_in[0];
    const float* trans  = (const float*)d_in[1];
    const float* motion = (const float*)d_in[2];
    const float* fdc    = (const float*)d_in[3];
    const int*   indice = (const int*)d_in[4];
    float* out = (float*)d_out;

    char* ws = (char*)d_ws;
    float*     acc    = (float*)ws;                          // @0
    float4*    c4     = (float4*)(ws + 4096);                // 256 KB
    _Float16*  bf16b  = (_Float16*)(ws + 4096 + 262144);     // 256 KB
    _Float16*  af16b  = (_Float16*)(ws + 4096 + 2*262144);   // 256 KB
    float*     sqf    = (float*)(ws + 4096 + 3*262144);      // 64 KB
    float*     keys   = (float*)(ws + 4096 + 3*262144 + 65536);  // 8*M*8*4 = 4 MB

    k_gather<<<MPTS/256, 256, 0, stream>>>(canon, trans, indice, c4, bf16b, af16b, sqf, acc);
    k_knn<<<(MPTS/16)*NSPLIT/4, 256, 0, stream>>>(bf16b, af16b, sqf, keys);
    k_merge_loss<<<MPTS/32, 256, 0, stream>>>(c4, keys, indice, motion, fdc, acc);
    k_final<<<1, 1, 0, stream>>>(acc, out);
}